// Round 4
// baseline (1057.115 us; speedup 1.0000x reference)
//
#include <hip/hip_runtime.h>
#include <math.h>

#define NROWS 131072
#define DIM   64
#define KCENT 1024
#define DECAY 0.99f
#define EPS_  1e-5f
#define CSTR  80   // centT row stride in floats: 64 dims + c_sq + pad -> 320B

// ---------------- ws layout (float elements) ----------------
// csum   [K*D]     @ 0        (written densely by k_segsum)
// cnt    [K]       @ 65536    (int, zeroed)
// cs     [K]       @ 66560
// cnewT  [K*D]     @ 67584    ([K][D] codebook for coalesced gather)
// ind    [N]       @ 133120   (int)
// perm   [N]       @ 264192   (int)
// start  [K]       @ 395264   (int)
// cursor [K]       @ 396288   (int)
// centT  [(K+2)*80]@ 397312   ([k][80]: 64 dims + ||c||^2 @ [64]; 2 pad rows for prefetch)
// total ~1.92 MB

// ---------- K1: transpose centroids to [K][80] rows + ||c_k||^2 ----------
__global__ void k_ctrans(const float* __restrict__ cent, float* __restrict__ centT) {
    int k = blockIdx.x * 256 + threadIdx.x;   // 0..1023
    float sq = 0.f;
#pragma unroll
    for (int d0 = 0; d0 < DIM; d0 += 4) {
        float4 v;
        v.x = cent[(d0 + 0) * KCENT + k];     // coalesced across lanes
        v.y = cent[(d0 + 1) * KCENT + k];
        v.z = cent[(d0 + 2) * KCENT + k];
        v.w = cent[(d0 + 3) * KCENT + k];
        sq = fmaf(v.x, v.x, fmaf(v.y, v.y, fmaf(v.z, v.z, fmaf(v.w, v.w, sq))));
        ((float4*)(centT + (size_t)k * CSTR))[d0 >> 2] = v;
    }
    centT[(size_t)k * CSTR + 64] = sq;
}

// ---------- K2: nearest-centroid assignment ----------
// launch_bounds(256,2): 2 blocks/CU (matches the grid-limited 8 waves/CU) ->
// 256-VGPR budget so xv[16] stays resident (r3 regression: VGPR capped at 40,
// x re-read from L1 every k). Centroid rows ping-pong prefetched (distance 1).
#define LOADROW(buf, row) do {                                   \
    const float4* _p = (const float4*)(centT + (size_t)(row) * CSTR); \
    _Pragma("unroll")                                            \
    for (int _i = 0; _i < 17; ++_i) buf[_i] = _p[_i];            \
} while (0)

#define DISTSTEP(buf, kk) do {                                   \
    float4 a = make_float4(0.f, 0.f, 0.f, 0.f);                  \
    _Pragma("unroll")                                            \
    for (int _i = 0; _i < 16; ++_i) {                            \
        float4 c = buf[_i];                                      \
        a.x = fmaf(xv[_i].x, c.x, a.x);                          \
        a.y = fmaf(xv[_i].y, c.y, a.y);                          \
        a.z = fmaf(xv[_i].z, c.z, a.z);                          \
        a.w = fmaf(xv[_i].w, c.w, a.w);                          \
    }                                                            \
    float dot  = (a.x + a.y) + (a.z + a.w);                      \
    float dist = buf[16].x - 2.0f * dot;                         \
    if (dist < best) { best = dist; bi = (kk); }                 \
} while (0)

__global__ __launch_bounds__(256, 2) void k_assign(
    const float* __restrict__ x, const float* __restrict__ centT,
    int* __restrict__ ind, int* __restrict__ cnt) {
    __shared__ int hist[KCENT];
#pragma unroll
    for (int i = 0; i < KCENT / 256; ++i) hist[threadIdx.x + i * 256] = 0;
    __syncthreads();

    const int n = blockIdx.x * 256 + threadIdx.x;
    float4 xv[16];
    const float4* xr = (const float4*)(x + (size_t)n * DIM);
#pragma unroll
    for (int i = 0; i < 16; ++i) xv[i] = xr[i];

    float best = 3.402823466e38f;
    int   bi   = 0;

    float4 bufA[17], bufB[17];
    LOADROW(bufA, 0);
    for (int k = 0; k < KCENT; k += 2) {
        LOADROW(bufB, k + 1);       // prefetch while computing on bufA
        DISTSTEP(bufA, k);
        LOADROW(bufA, k + 2);       // prefetch (pad rows make k=1022/1023 safe)
        DISTSTEP(bufB, k + 1);
    }

    ind[n] = bi;
    atomicAdd(&hist[bi], 1);          // LDS atomic
    __syncthreads();
#pragma unroll
    for (int i = 0; i < KCENT / 256; ++i) {
        int b = threadIdx.x + i * 256;
        int v = hist[b];
        if (v) atomicAdd(&cnt[b], v); // ~226 global atomics / block
    }
}

// ---------- K3: EMA stats + Laplace cs + exclusive prefix sum ----------
__global__ void k_scan(const float* __restrict__ cluster_size,
                       const int* __restrict__ cnt,
                       float* __restrict__ cs,
                       int* __restrict__ start, int* __restrict__ cursor) {
    __shared__ int   sa[KCENT], sb[KCENT];
    __shared__ float rf[KCENT];
    const int t = threadIdx.x;
    const int c = cnt[t];

    float cls = DECAY * cluster_size[t] + (1.0f - DECAY) * (float)c;
    rf[t] = cls;
    __syncthreads();
    for (int off = KCENT / 2; off > 0; off >>= 1) {
        if (t < off) rf[t] += rf[t + off];
        __syncthreads();
    }
    float ntot = rf[0];
    cs[t] = (cls + EPS_) / (ntot + KCENT * EPS_) * ntot;

    sa[t] = c;
    __syncthreads();
    int* pin = sa; int* pout = sb;
    for (int off = 1; off < KCENT; off <<= 1) {
        pout[t] = pin[t] + ((t >= off) ? pin[t - off] : 0);
        __syncthreads();
        int* tmp = pin; pin = pout; pout = tmp;
    }
    int excl = pin[t] - c;
    start[t]  = excl;
    cursor[t] = excl;
}

// ---------- K4: scatter rows into cluster-sorted order ----------
__global__ __launch_bounds__(256) void k_scatter(
    const int* __restrict__ ind, int* __restrict__ cursor,
    int* __restrict__ perm) {
    int n = blockIdx.x * 256 + threadIdx.x;
    int bi = ind[n];
    int pos = atomicAdd(&cursor[bi], 1);   // 131K atomics on 1024 addrs
    perm[pos] = n;
}

// ---------- K5: dense per-cluster segment sum (no atomics) ----------
__global__ __launch_bounds__(256) void k_segsum(
    const float* __restrict__ x, const int* __restrict__ perm,
    const int* __restrict__ start, const int* __restrict__ cnt,
    float* __restrict__ csum) {
    const int k = blockIdx.x;
    const int w = threadIdx.x >> 6;    // wave 0..3
    const int d = threadIdx.x & 63;    // dim
    const int s = start[k];
    const int c = cnt[k];

    float acc = 0.f;
    int r = w;
    for (; r + 4 < c; r += 8) {        // 2 rows in flight per iter
        int row0 = perm[s + r];
        int row1 = perm[s + r + 4];
        acc += x[(size_t)row0 * DIM + d];
        acc += x[(size_t)row1 * DIM + d];
    }
    for (; r < c; r += 4)
        acc += x[(size_t)perm[s + r] * DIM + d];

    __shared__ float red[256];
    red[threadIdx.x] = acc;
    __syncthreads();
    if (w == 0)
        csum[(size_t)k * DIM + d] = red[d] + red[64 + d] + red[128 + d] + red[192 + d];
}

// ---------- K6: centroids_new, stored transposed [K][D] ----------
__global__ void k_newcent(const float* __restrict__ avg,
                          const float* __restrict__ csum,
                          const float* __restrict__ cs,
                          float* __restrict__ cnewT) {
    int idx = blockIdx.x * blockDim.x + threadIdx.x;  // = k*64 + d
    int k = idx >> 6, d = idx & 63;
    float v = DECAY * avg[d * KCENT + k] + (1.0f - DECAY) * csum[idx];
    cnewT[idx] = v / cs[k];
}

// ---------- K7: gather quantized rows + MSE loss ----------
__global__ __launch_bounds__(256) void k_out(
    const float* __restrict__ x, const int* __restrict__ ind,
    const float* __restrict__ cnewT, float* __restrict__ out,
    float* __restrict__ loss) {
    const int tid = threadIdx.x;
    const int l16 = tid & 15;
    float p = 0.f;

    for (int g = blockIdx.x; g < NROWS / 16; g += 1024) {
        int row = g * 16 + (tid >> 4);  // 16 rows per iter, 16 lanes/row
        int k = ind[row];
        float4 q  = ((const float4*)(cnewT + (size_t)k * DIM))[l16];
        float4 xw = ((const float4*)(x + (size_t)row * DIM))[l16];
        ((float4*)(out + (size_t)row * DIM))[l16] = q;
        float dx = xw.x - q.x, dy = xw.y - q.y, dz = xw.z - q.z, dw = xw.w - q.w;
        p += dx * dx + dy * dy + dz * dz + dw * dw;
    }

    __shared__ float red[256];
    red[tid] = p;
    __syncthreads();
    for (int off = 128; off > 0; off >>= 1) {
        if (tid < off) red[tid] += red[tid + off];
        __syncthreads();
    }
    if (tid == 0)
        atomicAdd(loss, red[0] * (1.0f / ((float)NROWS * (float)DIM)));
}

extern "C" void kernel_launch(void* const* d_in, const int* in_sizes, int n_in,
                              void* d_out, int out_size, void* d_ws, size_t ws_size,
                              hipStream_t stream) {
    const float* x            = (const float*)d_in[0];
    const float* cent         = (const float*)d_in[1];
    const float* cluster_size = (const float*)d_in[2];
    const float* avg          = (const float*)d_in[3];
    float* out = (float*)d_out;

    float* ws     = (float*)d_ws;
    float* csum   = ws;                    // K*D
    int*   cnt    = (int*)(ws + 65536);    // K
    float* cs     = ws + 66560;            // K
    float* cnewT  = ws + 67584;            // K*D
    int*   ind    = (int*)(ws + 133120);   // N
    int*   perm   = (int*)(ws + 264192);   // N
    int*   start  = (int*)(ws + 395264);   // K
    int*   cursor = (int*)(ws + 396288);   // K
    float* centT  = ws + 397312;           // (K+2)*80

    hipMemsetAsync(cnt, 0, KCENT * sizeof(int), stream);
    hipMemsetAsync(out + (size_t)NROWS * DIM, 0, sizeof(float), stream);  // loss slot

    k_ctrans<<<KCENT / 256, 256, 0, stream>>>(cent, centT);
    k_assign<<<NROWS / 256, 256, 0, stream>>>(x, centT, ind, cnt);
    k_scan  <<<1, KCENT, 0, stream>>>(cluster_size, cnt, cs, start, cursor);
    k_scatter<<<NROWS / 256, 256, 0, stream>>>(ind, cursor, perm);
    k_segsum<<<KCENT, 256, 0, stream>>>(x, perm, start, cnt, csum);
    k_newcent<<<(KCENT * DIM) / 256, 256, 0, stream>>>(avg, csum, cs, cnewT);
    k_out   <<<1024, 256, 0, stream>>>(x, ind, cnewT, out,
                                       out + (size_t)NROWS * DIM);
}

// Round 5
// 375.430 us; speedup vs baseline: 2.8157x; 2.8157x over previous
//
#include <hip/hip_runtime.h>
#include <math.h>

#define NROWS 131072
#define DIM   64
#define KCENT 1024
#define DECAY 0.99f
#define EPS_  1e-5f

typedef unsigned int u32;
typedef unsigned short u16;
typedef __attribute__((ext_vector_type(8))) short short8b;
typedef __attribute__((ext_vector_type(16))) float floatx16;

// ---------------- ws layout (float elements) ----------------
// csum4   [4][K*D] @ 0        (dense partials, no zeroing needed)
// cnt     [K]      @ 262144   (int, zeroed)
// cs      [K]      @ 263168
// cnewT   [K*D]    @ 264192
// ind     [N]      @ 329728   (int)
// perm    [N]      @ 460800   (int)
// start   [K]      @ 591872   (int)
// cursor16[K*16]   @ 592896   (int, 64B-spread atomic cursors)
// centB   [K*132]  @ 609280   (u32: bf16 [hi|lo|hi|lo] 128dw + csq@128 + pad, stride 132dw=528B)

__device__ inline u16 bf16rne(float f) {
    u32 u = __float_as_uint(f);
    return (u16)((u + 0x7FFFu + ((u >> 16) & 1u)) >> 16);
}

// ---------- K1: centroids -> bf16 hi/lo split rows + ||c||^2 ----------
__global__ void k_ctrans(const float* __restrict__ cent, u32* __restrict__ centB) {
    int k = blockIdx.x * 256 + threadIdx.x;   // 0..1023
    u32* row = centB + (size_t)k * 132;
    float csq = 0.f;
#pragma unroll
    for (int d0 = 0; d0 < 32; ++d0) {
        float f0 = cent[(2 * d0) * KCENT + k];      // coalesced across lanes
        float f1 = cent[(2 * d0 + 1) * KCENT + k];
        u16 h0 = bf16rne(f0), h1 = bf16rne(f1);
        u16 s0 = bf16rne(f0 - __uint_as_float((u32)h0 << 16));
        u16 s1 = bf16rne(f1 - __uint_as_float((u32)h1 << 16));
        csq = fmaf(f0, f0, fmaf(f1, f1, csq));
        u32 hw = (u32)h0 | ((u32)h1 << 16);
        u32 lw = (u32)s0 | ((u32)s1 << 16);
        row[d0]      = hw;   // slice0: hi
        row[32 + d0] = lw;   // slice1: lo
        row[64 + d0] = hw;   // slice2: hi (dup)
        row[96 + d0] = lw;   // slice3: lo (dup)
    }
    row[128] = __float_as_uint(csq);
}

// ---------- K2: MFMA nearest-centroid assignment ----------
// A = x rows (hi|hi|lo|lo), B = cents (hi|lo|hi|lo) -> dot exact to ~1e-6.
// dist = csq - 2*dot (x_sq row-constant, irrelevant for argmin).
// C layout (measured m74/m101): col=lane&31, row=(reg&3)+8*(reg>>2)+4*(lane>>5).
__global__ __launch_bounds__(256, 3) void k_assign(
    const float* __restrict__ x, const u32* __restrict__ centB,
    int* __restrict__ ind, int* __restrict__ cnt) {
    __shared__ __align__(16) char buf[2][16896];   // 32 cents x 528B
    __shared__ int hist[KCENT];
    const int tid  = threadIdx.x;
    const int lane = tid & 63;
    const int wid  = tid >> 6;
    const int half = lane >> 5;
    const int nl   = lane & 31;
#pragma unroll
    for (int i = 0; i < KCENT / 256; ++i) hist[tid + i * 256] = 0;

    const int row = blockIdx.x * 128 + wid * 32 + nl;
    const float* xr = x + (size_t)row * DIM;

    // Build 16 A-frags: step t covers virtual k [t*16+half*8, +8)
    short8b afrag[16];
#pragma unroll
    for (int t = 0; t < 16; ++t) {
        int kv0 = t * 16 + half * 8;
        int d0  = kv0 & 63;
        bool lo_slice = kv0 >= 128;                 // slices 2,3 = lo
        float4 f0 = *(const float4*)(xr + d0);
        float4 f1 = *(const float4*)(xr + d0 + 4);
        float fv[8] = {f0.x, f0.y, f0.z, f0.w, f1.x, f1.y, f1.z, f1.w};
        short8b a;
#pragma unroll
        for (int j = 0; j < 8; ++j) {
            u16 h = bf16rne(fv[j]);
            if (lo_slice)
                h = bf16rne(fv[j] - __uint_as_float((u32)h << 16));
            a[j] = (short)h;
        }
        afrag[t] = a;
    }

    float best[16];
    int   bidx[16];
#pragma unroll
    for (int r = 0; r < 16; ++r) { best[r] = 3.402823466e38f; bidx[r] = 0; }

    // tile = 32 cents = 1056 granules of 16B
    const float4* gsrc = (const float4*)centB;
    float4 pf0, pf1, pf2, pf3, pf4;
    {
        size_t gb = (size_t)0;
        pf0 = gsrc[gb + tid];
        pf1 = gsrc[gb + tid + 256];
        pf2 = gsrc[gb + tid + 512];
        pf3 = gsrc[gb + tid + 768];
        if (tid < 32) pf4 = gsrc[gb + tid + 1024];
    }

    for (int kt = 0; kt < 32; ++kt) {
        char* b = buf[kt & 1];
        *(float4*)(b + (size_t)tid * 16)          = pf0;
        *(float4*)(b + (size_t)(tid + 256) * 16)  = pf1;
        *(float4*)(b + (size_t)(tid + 512) * 16)  = pf2;
        *(float4*)(b + (size_t)(tid + 768) * 16)  = pf3;
        if (tid < 32) *(float4*)(b + (size_t)(tid + 1024) * 16) = pf4;
        __syncthreads();
        if (kt < 31) {                               // prefetch next tile
            size_t gb = (size_t)(kt + 1) * 1056;
            pf0 = gsrc[gb + tid];
            pf1 = gsrc[gb + tid + 256];
            pf2 = gsrc[gb + tid + 512];
            pf3 = gsrc[gb + tid + 768];
            if (tid < 32) pf4 = gsrc[gb + tid + 1024];
        }

        floatx16 acc;
#pragma unroll
        for (int i = 0; i < 16; ++i) acc[i] = 0.f;
        const char* bb = b + (size_t)nl * 528 + half * 16;
#pragma unroll
        for (int t = 0; t < 16; ++t) {
            short8b bf = *(const short8b*)(bb + t * 32);
            acc = __builtin_amdgcn_mfma_f32_32x32x16_bf16(afrag[t], bf, acc, 0, 0, 0);
        }
        float cq  = *(const float*)(b + (size_t)nl * 528 + 512);
        int  cidx = kt * 32 + nl;
#pragma unroll
        for (int r = 0; r < 16; ++r) {
            float dist = fmaf(-2.0f, acc[r], cq);
            if (dist < best[r]) { best[r] = dist; bidx[r] = cidx; }
        }
        __syncthreads();
    }

    // cross-lane argmin: each C row lives in 32 lanes (same half)
#pragma unroll
    for (int r = 0; r < 16; ++r) {
        float b0 = best[r]; int i0 = bidx[r];
#pragma unroll
        for (int m = 1; m < 32; m <<= 1) {
            float bp = __shfl_xor(b0, m, 64);
            int   ip = __shfl_xor(i0, m, 64);
            if (bp < b0 || (bp == b0 && ip < i0)) { b0 = bp; i0 = ip; }
        }
        best[r] = b0; bidx[r] = i0;
    }
    if (nl == 0) {
        int rb = blockIdx.x * 128 + wid * 32;
#pragma unroll
        for (int r = 0; r < 16; ++r) {
            int m = (r & 3) + 8 * (r >> 2) + 4 * half;
            ind[rb + m] = bidx[r];
            atomicAdd(&hist[bidx[r]], 1);
        }
    }
    __syncthreads();
#pragma unroll
    for (int i = 0; i < KCENT / 256; ++i) {
        int bkt = tid + i * 256;
        int v = hist[bkt];
        if (v) atomicAdd(&cnt[bkt], v);
    }
}

// ---------- K3: EMA stats + Laplace cs + exclusive prefix sum ----------
__global__ void k_scan(const float* __restrict__ cluster_size,
                       const int* __restrict__ cnt,
                       float* __restrict__ cs,
                       int* __restrict__ start, int* __restrict__ cursor16) {
    __shared__ int   sa[KCENT], sb[KCENT];
    __shared__ float rf[KCENT];
    const int t = threadIdx.x;
    const int c = cnt[t];

    float cls = DECAY * cluster_size[t] + (1.0f - DECAY) * (float)c;
    rf[t] = cls;
    __syncthreads();
    for (int off = KCENT / 2; off > 0; off >>= 1) {
        if (t < off) rf[t] += rf[t + off];
        __syncthreads();
    }
    float ntot = rf[0];
    cs[t] = (cls + EPS_) / (ntot + KCENT * EPS_) * ntot;

    sa[t] = c;
    __syncthreads();
    int* pin = sa; int* pout = sb;
    for (int off = 1; off < KCENT; off <<= 1) {
        pout[t] = pin[t] + ((t >= off) ? pin[t - off] : 0);
        __syncthreads();
        int* tmp = pin; pin = pout; pout = tmp;
    }
    int excl = pin[t] - c;
    start[t] = excl;
    cursor16[t * 16] = excl;   // one cursor per 64B line -> parallel atomic chains
}

// ---------- K4: scatter rows into cluster-sorted order ----------
__global__ __launch_bounds__(256) void k_scatter(
    const int* __restrict__ ind, int* __restrict__ cursor16,
    int* __restrict__ perm) {
    int n = blockIdx.x * 256 + threadIdx.x;
    int bi = ind[n];
    int pos = atomicAdd(&cursor16[bi * 16], 1);
    perm[pos] = n;
}

// ---------- K5: per-cluster segment sum, 4 chunks/cluster (tail /4) ----------
__global__ __launch_bounds__(256) void k_segsum(
    const float* __restrict__ x, const int* __restrict__ perm,
    const int* __restrict__ start, const int* __restrict__ cnt,
    float* __restrict__ csum4) {
    const int k = blockIdx.x >> 2;
    const int j = blockIdx.x & 3;
    const int w = threadIdx.x >> 6;    // wave 0..3
    const int d = threadIdx.x & 63;    // dim
    const int c  = cnt[k];
    const int r0 = (c * j) >> 2;
    const int r1 = (c * (j + 1)) >> 2;
    const int s  = start[k] + r0;
    const int n  = r1 - r0;

    float acc = 0.f;
    int r = w;
    for (; r + 4 < n; r += 8) {
        int rowa = perm[s + r];
        int rowb = perm[s + r + 4];
        acc += x[(size_t)rowa * DIM + d];
        acc += x[(size_t)rowb * DIM + d];
    }
    for (; r < n; r += 4)
        acc += x[(size_t)perm[s + r] * DIM + d];

    __shared__ float red[256];
    red[threadIdx.x] = acc;
    __syncthreads();
    if (w == 0)
        csum4[(size_t)j * (KCENT * DIM) + (size_t)k * DIM + d] =
            red[d] + red[64 + d] + red[128 + d] + red[192 + d];
}

// ---------- K6: centroids_new, stored transposed [K][D] ----------
__global__ void k_newcent(const float* __restrict__ avg,
                          const float* __restrict__ csum4,
                          const float* __restrict__ cs,
                          float* __restrict__ cnewT) {
    int idx = blockIdx.x * blockDim.x + threadIdx.x;  // = k*64 + d
    int k = idx >> 6, d = idx & 63;
    float ssum = csum4[idx] + csum4[KCENT * DIM + idx] +
                 csum4[2 * KCENT * DIM + idx] + csum4[3 * KCENT * DIM + idx];
    float v = DECAY * avg[d * KCENT + k] + (1.0f - DECAY) * ssum;
    cnewT[idx] = v / cs[k];
}

// ---------- K7: gather quantized rows + MSE loss ----------
__global__ __launch_bounds__(256) void k_out(
    const float* __restrict__ x, const int* __restrict__ ind,
    const float* __restrict__ cnewT, float* __restrict__ out,
    float* __restrict__ loss) {
    const int tid = threadIdx.x;
    const int l16 = tid & 15;
    float p = 0.f;

    for (int g = blockIdx.x; g < NROWS / 16; g += 1024) {
        int row = g * 16 + (tid >> 4);
        int k = ind[row];
        float4 q  = ((const float4*)(cnewT + (size_t)k * DIM))[l16];
        float4 xw = ((const float4*)(x + (size_t)row * DIM))[l16];
        ((float4*)(out + (size_t)row * DIM))[l16] = q;
        float dx = xw.x - q.x, dy = xw.y - q.y, dz = xw.z - q.z, dw = xw.w - q.w;
        p += dx * dx + dy * dy + dz * dz + dw * dw;
    }

    __shared__ float red[256];
    red[tid] = p;
    __syncthreads();
    for (int off = 128; off > 0; off >>= 1) {
        if (tid < off) red[tid] += red[tid + off];
        __syncthreads();
    }
    if (tid == 0)
        atomicAdd(loss, red[0] * (1.0f / ((float)NROWS * (float)DIM)));
}

extern "C" void kernel_launch(void* const* d_in, const int* in_sizes, int n_in,
                              void* d_out, int out_size, void* d_ws, size_t ws_size,
                              hipStream_t stream) {
    const float* x            = (const float*)d_in[0];
    const float* cent         = (const float*)d_in[1];
    const float* cluster_size = (const float*)d_in[2];
    const float* avg          = (const float*)d_in[3];
    float* out = (float*)d_out;

    float* ws       = (float*)d_ws;
    float* csum4    = ws;                     // 4*K*D
    int*   cnt      = (int*)(ws + 262144);    // K
    float* cs       = ws + 263168;            // K
    float* cnewT    = ws + 264192;            // K*D
    int*   ind      = (int*)(ws + 329728);    // N
    int*   perm     = (int*)(ws + 460800);    // N
    int*   start    = (int*)(ws + 591872);    // K
    int*   cursor16 = (int*)(ws + 592896);    // 16K
    u32*   centB    = (u32*)(ws + 609280);    // K*132

    hipMemsetAsync(cnt, 0, KCENT * sizeof(int), stream);
    hipMemsetAsync(out + (size_t)NROWS * DIM, 0, sizeof(float), stream);  // loss slot

    k_ctrans <<<KCENT / 256, 256, 0, stream>>>(cent, centB);
    k_assign <<<NROWS / 128, 256, 0, stream>>>(x, centB, ind, cnt);
    k_scan   <<<1, KCENT, 0, stream>>>(cluster_size, cnt, cs, start, cursor16);
    k_scatter<<<NROWS / 256, 256, 0, stream>>>(ind, cursor16, perm);
    k_segsum <<<4 * KCENT, 256, 0, stream>>>(x, perm, start, cnt, csum4);
    k_newcent<<<(KCENT * DIM) / 256, 256, 0, stream>>>(avg, csum4, cs, cnewT);
    k_out    <<<1024, 256, 0, stream>>>(x, ind, cnewT, out,
                                        out + (size_t)NROWS * DIM);
}

// Round 6
// 295.895 us; speedup vs baseline: 3.5726x; 1.2688x over previous
//
#include <hip/hip_runtime.h>
#include <math.h>

#define NROWS 131072
#define DIM   64
#define KCENT 1024
#define DECAY 0.99f
#define EPS_  1e-5f

typedef unsigned int u32;
typedef unsigned short u16;
typedef __attribute__((ext_vector_type(8))) short short8b;
typedef __attribute__((ext_vector_type(16))) float floatx16;

// ---------------- ws layout (float elements) ----------------
// csum    [K*D]    @ 0        (zeroed; fp32 atomic flush targets)
// cnt     [K]      @ 65536    (int, zeroed — contiguous with csum for one memset)
// cs      [K]      @ 66560
// cnewT   [K*D]    @ 67584
// ind     [N]      @ 133120   (int)
// perm    [N]      @ 264192   (int)
// key     [N]      @ 395264   (int: cluster id in sorted order)
// start   [K]      @ 526336   (int)
// cursor16[K*16]   @ 527360   (int, 64B-spread atomic cursors)
// centB   [K*132]  @ 543744   (u32: bf16 [hi|lo|hi|lo] 128dw + csq@128, stride 132dw)

__device__ inline u16 bf16rne(float f) {
    u32 u = __float_as_uint(f);
    return (u16)((u + 0x7FFFu + ((u >> 16) & 1u)) >> 16);
}

// ---------- K1: centroids -> bf16 hi/lo split rows + ||c||^2 ----------
__global__ void k_ctrans(const float* __restrict__ cent, u32* __restrict__ centB) {
    int k = blockIdx.x * 256 + threadIdx.x;   // 0..1023
    u32* row = centB + (size_t)k * 132;
    float csq = 0.f;
#pragma unroll
    for (int d0 = 0; d0 < 32; ++d0) {
        float f0 = cent[(2 * d0) * KCENT + k];      // coalesced across lanes
        float f1 = cent[(2 * d0 + 1) * KCENT + k];
        u16 h0 = bf16rne(f0), h1 = bf16rne(f1);
        u16 s0 = bf16rne(f0 - __uint_as_float((u32)h0 << 16));
        u16 s1 = bf16rne(f1 - __uint_as_float((u32)h1 << 16));
        csq = fmaf(f0, f0, fmaf(f1, f1, csq));
        u32 hw = (u32)h0 | ((u32)h1 << 16);
        u32 lw = (u32)s0 | ((u32)s1 << 16);
        row[d0]      = hw;   // slice0: hi
        row[32 + d0] = lw;   // slice1: lo
        row[64 + d0] = hw;   // slice2: hi (dup)
        row[96 + d0] = lw;   // slice3: lo (dup)
    }
    row[128] = __float_as_uint(csq);
}

// ---------- K2: MFMA nearest-centroid assignment ----------
// A = x rows (hi|hi|lo|lo), B = cents (hi|lo|hi|lo) -> dot exact to ~1e-6.
// C layout (measured m74/m101): col=lane&31, row=(reg&3)+8*(reg>>2)+4*(lane>>5).
__global__ __launch_bounds__(256, 3) void k_assign(
    const float* __restrict__ x, const u32* __restrict__ centB,
    int* __restrict__ ind, int* __restrict__ cnt) {
    __shared__ __align__(16) char buf[2][16896];   // 32 cents x 528B
    __shared__ int hist[KCENT];
    const int tid  = threadIdx.x;
    const int lane = tid & 63;
    const int wid  = tid >> 6;
    const int half = lane >> 5;
    const int nl   = lane & 31;
#pragma unroll
    for (int i = 0; i < KCENT / 256; ++i) hist[tid + i * 256] = 0;

    const int row = blockIdx.x * 128 + wid * 32 + nl;
    const float* xr = x + (size_t)row * DIM;

    // Build 16 A-frags: step t covers virtual k [t*16+half*8, +8)
    short8b afrag[16];
#pragma unroll
    for (int t = 0; t < 16; ++t) {
        int kv0 = t * 16 + half * 8;
        int d0  = kv0 & 63;
        bool lo_slice = kv0 >= 128;                 // slices 2,3 = lo
        float4 f0 = *(const float4*)(xr + d0);
        float4 f1 = *(const float4*)(xr + d0 + 4);
        float fv[8] = {f0.x, f0.y, f0.z, f0.w, f1.x, f1.y, f1.z, f1.w};
        short8b a;
#pragma unroll
        for (int j = 0; j < 8; ++j) {
            u16 h = bf16rne(fv[j]);
            if (lo_slice)
                h = bf16rne(fv[j] - __uint_as_float((u32)h << 16));
            a[j] = (short)h;
        }
        afrag[t] = a;
    }

    float best[16];
    int   bidx[16];
#pragma unroll
    for (int r = 0; r < 16; ++r) { best[r] = 3.402823466e38f; bidx[r] = 0; }

    // tile = 32 cents = 1056 granules of 16B
    const float4* gsrc = (const float4*)centB;
    float4 pf0, pf1, pf2, pf3, pf4;
    {
        pf0 = gsrc[tid];
        pf1 = gsrc[tid + 256];
        pf2 = gsrc[tid + 512];
        pf3 = gsrc[tid + 768];
        if (tid < 32) pf4 = gsrc[tid + 1024];
    }

    for (int kt = 0; kt < 32; ++kt) {
        char* b = buf[kt & 1];
        *(float4*)(b + (size_t)tid * 16)          = pf0;
        *(float4*)(b + (size_t)(tid + 256) * 16)  = pf1;
        *(float4*)(b + (size_t)(tid + 512) * 16)  = pf2;
        *(float4*)(b + (size_t)(tid + 768) * 16)  = pf3;
        if (tid < 32) *(float4*)(b + (size_t)(tid + 1024) * 16) = pf4;
        __syncthreads();
        if (kt < 31) {                               // prefetch next tile
            size_t gb = (size_t)(kt + 1) * 1056;
            pf0 = gsrc[gb + tid];
            pf1 = gsrc[gb + tid + 256];
            pf2 = gsrc[gb + tid + 512];
            pf3 = gsrc[gb + tid + 768];
            if (tid < 32) pf4 = gsrc[gb + tid + 1024];
        }

        floatx16 acc;
#pragma unroll
        for (int i = 0; i < 16; ++i) acc[i] = 0.f;
        const char* bb = b + (size_t)nl * 528 + half * 16;
#pragma unroll
        for (int t = 0; t < 16; ++t) {
            short8b bf = *(const short8b*)(bb + t * 32);
            acc = __builtin_amdgcn_mfma_f32_32x32x16_bf16(afrag[t], bf, acc, 0, 0, 0);
        }
        float cq  = *(const float*)(b + (size_t)nl * 528 + 512);
        int  cidx = kt * 32 + nl;
#pragma unroll
        for (int r = 0; r < 16; ++r) {
            float dist = fmaf(-2.0f, acc[r], cq);
            if (dist < best[r]) { best[r] = dist; bidx[r] = cidx; }
        }
        __syncthreads();
    }

    // cross-lane argmin: each C row lives in 32 lanes (same half)
#pragma unroll
    for (int r = 0; r < 16; ++r) {
        float b0 = best[r]; int i0 = bidx[r];
#pragma unroll
        for (int m = 1; m < 32; m <<= 1) {
            float bp = __shfl_xor(b0, m, 64);
            int   ip = __shfl_xor(i0, m, 64);
            if (bp < b0 || (bp == b0 && ip < i0)) { b0 = bp; i0 = ip; }
        }
        best[r] = b0; bidx[r] = i0;
    }
    if (nl == 0) {
        int rb = blockIdx.x * 128 + wid * 32;
#pragma unroll
        for (int r = 0; r < 16; ++r) {
            int m = (r & 3) + 8 * (r >> 2) + 4 * half;
            ind[rb + m] = bidx[r];
            atomicAdd(&hist[bidx[r]], 1);
        }
    }
    __syncthreads();
#pragma unroll
    for (int i = 0; i < KCENT / 256; ++i) {
        int bkt = tid + i * 256;
        int v = hist[bkt];
        if (v) atomicAdd(&cnt[bkt], v);
    }
}

// ---------- K3: EMA stats + Laplace cs + exclusive prefix sum ----------
__global__ void k_scan(const float* __restrict__ cluster_size,
                       const int* __restrict__ cnt,
                       float* __restrict__ cs,
                       int* __restrict__ start, int* __restrict__ cursor16) {
    __shared__ int   sa[KCENT], sb[KCENT];
    __shared__ float rf[KCENT];
    const int t = threadIdx.x;
    const int c = cnt[t];

    float cls = DECAY * cluster_size[t] + (1.0f - DECAY) * (float)c;
    rf[t] = cls;
    __syncthreads();
    for (int off = KCENT / 2; off > 0; off >>= 1) {
        if (t < off) rf[t] += rf[t + off];
        __syncthreads();
    }
    float ntot = rf[0];
    cs[t] = (cls + EPS_) / (ntot + KCENT * EPS_) * ntot;

    sa[t] = c;
    __syncthreads();
    int* pin = sa; int* pout = sb;
    for (int off = 1; off < KCENT; off <<= 1) {
        pout[t] = pin[t] + ((t >= off) ? pin[t - off] : 0);
        __syncthreads();
        int* tmp = pin; pin = pout; pout = tmp;
    }
    int excl = pin[t] - c;
    start[t] = excl;
    cursor16[t * 16] = excl;   // one cursor per 64B line
}

// ---------- K4: scatter rows into cluster-sorted order (+sorted keys) ----------
__global__ __launch_bounds__(256) void k_scatter(
    const int* __restrict__ ind, int* __restrict__ cursor16,
    int* __restrict__ perm, int* __restrict__ key) {
    int n = blockIdx.x * 256 + threadIdx.x;
    int bi = ind[n];
    int pos = atomicAdd(&cursor16[bi * 16], 1);
    perm[pos] = n;
    key[pos]  = bi;
}

// ---------- K5: segment sum over uniform 32-row wave-windows ----------
// Size-oblivious: no per-cluster tail. Flush atomics only at segment
// boundaries (~5K flushes x 64 lanes total).
__global__ __launch_bounds__(256) void k_segsum(
    const float* __restrict__ x, const int* __restrict__ perm,
    const int* __restrict__ key, float* __restrict__ csum) {
    const int wgid = blockIdx.x * 4 + (threadIdx.x >> 6);  // 0..4095
    const int lane = threadIdx.x & 63;
    const int r0   = wgid * 32;

    float acc = 0.f;
    int cur = key[r0];
#pragma unroll 4
    for (int r = r0; r < r0 + 32; r += 2) {
        int k0 = key[r];                  // wave-uniform -> scalar load
        int k1 = key[r + 1];
        int p0 = perm[r];
        int p1 = perm[r + 1];
        float v0 = x[(size_t)p0 * DIM + lane];   // coalesced 256B/row
        float v1 = x[(size_t)p1 * DIM + lane];
        if (k0 != cur) {                  // wave-uniform branch, rare
            atomicAdd(&csum[(size_t)cur * DIM + lane], acc);
            acc = 0.f; cur = k0;
        }
        acc += v0;
        if (k1 != cur) {
            atomicAdd(&csum[(size_t)cur * DIM + lane], acc);
            acc = 0.f; cur = k1;
        }
        acc += v1;
    }
    atomicAdd(&csum[(size_t)cur * DIM + lane], acc);
}

// ---------- K6: centroids_new, stored transposed [K][D] ----------
__global__ void k_newcent(const float* __restrict__ avg,
                          const float* __restrict__ csum,
                          const float* __restrict__ cs,
                          float* __restrict__ cnewT) {
    int idx = blockIdx.x * blockDim.x + threadIdx.x;  // = k*64 + d
    int k = idx >> 6, d = idx & 63;
    float v = DECAY * avg[d * KCENT + k] + (1.0f - DECAY) * csum[idx];
    cnewT[idx] = v / cs[k];
}

// ---------- K7: gather quantized rows + MSE loss ----------
__global__ __launch_bounds__(256) void k_out(
    const float* __restrict__ x, const int* __restrict__ ind,
    const float* __restrict__ cnewT, float* __restrict__ out,
    float* __restrict__ loss) {
    const int tid = threadIdx.x;
    const int l16 = tid & 15;
    float p = 0.f;

    for (int g = blockIdx.x; g < NROWS / 16; g += 1024) {
        int row = g * 16 + (tid >> 4);
        int k = ind[row];
        float4 q  = ((const float4*)(cnewT + (size_t)k * DIM))[l16];
        float4 xw = ((const float4*)(x + (size_t)row * DIM))[l16];
        ((float4*)(out + (size_t)row * DIM))[l16] = q;
        float dx = xw.x - q.x, dy = xw.y - q.y, dz = xw.z - q.z, dw = xw.w - q.w;
        p += dx * dx + dy * dy + dz * dz + dw * dw;
    }

    __shared__ float red[256];
    red[tid] = p;
    __syncthreads();
    for (int off = 128; off > 0; off >>= 1) {
        if (tid < off) red[tid] += red[tid + off];
        __syncthreads();
    }
    if (tid == 0)
        atomicAdd(loss, red[0] * (1.0f / ((float)NROWS * (float)DIM)));
}

extern "C" void kernel_launch(void* const* d_in, const int* in_sizes, int n_in,
                              void* d_out, int out_size, void* d_ws, size_t ws_size,
                              hipStream_t stream) {
    const float* x            = (const float*)d_in[0];
    const float* cent         = (const float*)d_in[1];
    const float* cluster_size = (const float*)d_in[2];
    const float* avg          = (const float*)d_in[3];
    float* out = (float*)d_out;

    float* ws       = (float*)d_ws;
    float* csum     = ws;                     // K*D (zeroed)
    int*   cnt      = (int*)(ws + 65536);     // K (zeroed, contiguous with csum)
    float* cs       = ws + 66560;             // K
    float* cnewT    = ws + 67584;             // K*D
    int*   ind      = (int*)(ws + 133120);    // N
    int*   perm     = (int*)(ws + 264192);    // N
    int*   key      = (int*)(ws + 395264);    // N
    int*   start    = (int*)(ws + 526336);    // K
    int*   cursor16 = (int*)(ws + 527360);    // 16K
    u32*   centB    = (u32*)(ws + 543744);    // K*132

    hipMemsetAsync(csum, 0, (65536 + 1024) * sizeof(float), stream);  // csum + cnt
    hipMemsetAsync(out + (size_t)NROWS * DIM, 0, sizeof(float), stream);  // loss slot

    k_ctrans <<<KCENT / 256, 256, 0, stream>>>(cent, centB);
    k_assign <<<NROWS / 128, 256, 0, stream>>>(x, centB, ind, cnt);
    k_scan   <<<1, KCENT, 0, stream>>>(cluster_size, cnt, cs, start, cursor16);
    k_scatter<<<NROWS / 256, 256, 0, stream>>>(ind, cursor16, perm, key);
    k_segsum <<<NROWS / 128, 256, 0, stream>>>(x, perm, key, csum);
    k_newcent<<<(KCENT * DIM) / 256, 256, 0, stream>>>(avg, csum, cs, cnewT);
    k_out    <<<1024, 256, 0, stream>>>(x, ind, cnewT, out,
                                        out + (size_t)NROWS * DIM);
}

// Round 7
// 294.387 us; speedup vs baseline: 3.5909x; 1.0051x over previous
//
#include <hip/hip_runtime.h>
#include <math.h>

#define NROWS 131072
#define DIM   64
#define KCENT 1024
#define DECAY 0.99f
#define EPS_  1e-5f

typedef unsigned int u32;
typedef unsigned short u16;
typedef __attribute__((ext_vector_type(8))) short short8b;
typedef __attribute__((ext_vector_type(16))) float floatx16;

// ---------------- ws layout (float elements) ----------------
// csum    [K*D]    @ 0        (zeroed; fp32 atomic flush targets)
// cnt     [K]      @ 65536    (int, zeroed — contiguous with csum for one memset)
// cs      [K]      @ 66560
// cnewT   [K*D]    @ 67584
// ind     [N]      @ 133120   (int)
// perm    [N]      @ 264192   (int)
// key     [N]      @ 395264   (int: cluster id in sorted order)
// start   [K]      @ 526336   (int)
// cursor16[K*16]   @ 527360   (int, 64B-spread atomic cursors)
// centB   [K*68]   @ 543744   (u32: bf16 hi 32dw | lo 32dw | csq@64 | pad; stride 68dw=272B)

__device__ inline u16 bf16rne(float f) {
    u32 u = __float_as_uint(f);
    return (u16)((u + 0x7FFFu + ((u >> 16) & 1u)) >> 16);
}

// ---------- K1: centroids -> dedup'd bf16 hi/lo rows + ||c||^2 ----------
__global__ void k_ctrans(const float* __restrict__ cent, u32* __restrict__ centB) {
    int k = blockIdx.x * 256 + threadIdx.x;   // 0..1023
    u32* row = centB + (size_t)k * 68;
    float csq = 0.f;
#pragma unroll
    for (int d0 = 0; d0 < 32; ++d0) {
        float f0 = cent[(2 * d0) * KCENT + k];      // coalesced across lanes
        float f1 = cent[(2 * d0 + 1) * KCENT + k];
        u16 h0 = bf16rne(f0), h1 = bf16rne(f1);
        u16 s0 = bf16rne(f0 - __uint_as_float((u32)h0 << 16));
        u16 s1 = bf16rne(f1 - __uint_as_float((u32)h1 << 16));
        csq = fmaf(f0, f0, fmaf(f1, f1, csq));
        row[d0]      = (u32)h0 | ((u32)h1 << 16);   // hi
        row[32 + d0] = (u32)s0 | ((u32)s1 << 16);   // lo
    }
    row[64] = __float_as_uint(csq);
}

// ---------- K2: MFMA nearest-centroid assignment, M=64/wave ----------
// Exact 2-term split: dot = xh.ch + xh.cl + xl.ch + xl.cl, 16 MFMA/tile/rowgroup
// from only 8 distinct A-frags and 8 distinct B-frags (hi/lo dedup).
// C layout (measured m74/m101): col=lane&31, row=(reg&3)+8*(reg>>2)+4*(lane>>5).
__global__ __launch_bounds__(256, 2) void k_assign(
    const float* __restrict__ x, const u32* __restrict__ centB,
    int* __restrict__ ind, int* __restrict__ cnt) {
    __shared__ __align__(16) char buf[2][8704];   // 32 cents x 272B
    __shared__ int hist[KCENT];
    const int tid  = threadIdx.x;
    const int lane = tid & 63;
    const int wid  = tid >> 6;
    const int half = lane >> 5;
    const int nl   = lane & 31;
#pragma unroll
    for (int i = 0; i < KCENT / 256; ++i) hist[tid + i * 256] = 0;

    const int rowbase = blockIdx.x * 256 + wid * 64;

    // Build A-frags: 4 hi + 4 lo per row-group (dims t4*16+half*8 .. +8)
    short8b ah[2][4], al[2][4];
#pragma unroll
    for (int rg = 0; rg < 2; ++rg) {
        const float* xr = x + (size_t)(rowbase + rg * 32 + nl) * DIM;
#pragma unroll
        for (int t4 = 0; t4 < 4; ++t4) {
            int d0 = t4 * 16 + half * 8;
            float4 f0 = *(const float4*)(xr + d0);
            float4 f1 = *(const float4*)(xr + d0 + 4);
            float fv[8] = {f0.x, f0.y, f0.z, f0.w, f1.x, f1.y, f1.z, f1.w};
            short8b va, vb;
#pragma unroll
            for (int j = 0; j < 8; ++j) {
                u16 h = bf16rne(fv[j]);
                float lo = fv[j] - __uint_as_float((u32)h << 16);
                va[j] = (short)h;
                vb[j] = (short)bf16rne(lo);
            }
            ah[rg][t4] = va;
            al[rg][t4] = vb;
        }
    }

    float best[2][16];
    int   bidx[2][16];
#pragma unroll
    for (int rg = 0; rg < 2; ++rg)
#pragma unroll
        for (int r = 0; r < 16; ++r) { best[rg][r] = 3.402823466e38f; bidx[rg][r] = 0; }

    // tile = 32 cents = 544 granules of 16B
    const float4* gsrc = (const float4*)centB;
    float4 pf0, pf1, pf2;
    pf0 = gsrc[tid];
    pf1 = gsrc[tid + 256];
    if (tid < 32) pf2 = gsrc[tid + 512];

    for (int kt = 0; kt < 32; ++kt) {
        char* b = buf[kt & 1];
        *(float4*)(b + (size_t)tid * 16)         = pf0;
        *(float4*)(b + (size_t)(tid + 256) * 16) = pf1;
        if (tid < 32) *(float4*)(b + (size_t)(tid + 512) * 16) = pf2;
        __syncthreads();
        if (kt < 31) {                               // prefetch next tile
            size_t gb = (size_t)(kt + 1) * 544;
            pf0 = gsrc[gb + tid];
            pf1 = gsrc[gb + tid + 256];
            if (tid < 32) pf2 = gsrc[gb + tid + 512];
        }

        const char* base = b + (size_t)nl * 272 + half * 16;
        short8b bh[4], bl[4];
#pragma unroll
        for (int t4 = 0; t4 < 4; ++t4) bh[t4] = *(const short8b*)(base + t4 * 32);
#pragma unroll
        for (int t4 = 0; t4 < 4; ++t4) bl[t4] = *(const short8b*)(base + 128 + t4 * 32);
        float cq  = *(const float*)(b + (size_t)nl * 272 + 256);
        int  cidx = kt * 32 + nl;

#pragma unroll
        for (int rg = 0; rg < 2; ++rg) {
            floatx16 acc;
#pragma unroll
            for (int i = 0; i < 16; ++i) acc[i] = 0.f;
#pragma unroll
            for (int t4 = 0; t4 < 4; ++t4)
                acc = __builtin_amdgcn_mfma_f32_32x32x16_bf16(ah[rg][t4], bh[t4], acc, 0, 0, 0);
#pragma unroll
            for (int t4 = 0; t4 < 4; ++t4)
                acc = __builtin_amdgcn_mfma_f32_32x32x16_bf16(ah[rg][t4], bl[t4], acc, 0, 0, 0);
#pragma unroll
            for (int t4 = 0; t4 < 4; ++t4)
                acc = __builtin_amdgcn_mfma_f32_32x32x16_bf16(al[rg][t4], bh[t4], acc, 0, 0, 0);
#pragma unroll
            for (int t4 = 0; t4 < 4; ++t4)
                acc = __builtin_amdgcn_mfma_f32_32x32x16_bf16(al[rg][t4], bl[t4], acc, 0, 0, 0);
#pragma unroll
            for (int r = 0; r < 16; ++r) {
                float dist = fmaf(-2.0f, acc[r], cq);
                if (dist < best[rg][r]) { best[rg][r] = dist; bidx[rg][r] = cidx; }
            }
        }
        __syncthreads();
    }

    // cross-lane argmin within each 32-lane half, then write winners
#pragma unroll
    for (int rg = 0; rg < 2; ++rg) {
#pragma unroll
        for (int r = 0; r < 16; ++r) {
            float b0 = best[rg][r]; int i0 = bidx[rg][r];
#pragma unroll
            for (int m = 1; m < 32; m <<= 1) {
                float bp = __shfl_xor(b0, m, 64);
                int   ip = __shfl_xor(i0, m, 64);
                if (bp < b0 || (bp == b0 && ip < i0)) { b0 = bp; i0 = ip; }
            }
            best[rg][r] = b0; bidx[rg][r] = i0;
        }
    }
    if (nl == 0) {
#pragma unroll
        for (int rg = 0; rg < 2; ++rg) {
            int rb = rowbase + rg * 32;
#pragma unroll
            for (int r = 0; r < 16; ++r) {
                int m = (r & 3) + 8 * (r >> 2) + 4 * half;
                ind[rb + m] = bidx[rg][r];
                atomicAdd(&hist[bidx[rg][r]], 1);
            }
        }
    }
    __syncthreads();
#pragma unroll
    for (int i = 0; i < KCENT / 256; ++i) {
        int bkt = tid + i * 256;
        int v = hist[bkt];
        if (v) atomicAdd(&cnt[bkt], v);
    }
}

// ---------- K3: EMA stats + Laplace cs + exclusive prefix sum ----------
__global__ void k_scan(const float* __restrict__ cluster_size,
                       const int* __restrict__ cnt,
                       float* __restrict__ cs,
                       int* __restrict__ start, int* __restrict__ cursor16) {
    __shared__ int   sa[KCENT], sb[KCENT];
    __shared__ float rf[KCENT];
    const int t = threadIdx.x;
    const int c = cnt[t];

    float cls = DECAY * cluster_size[t] + (1.0f - DECAY) * (float)c;
    rf[t] = cls;
    __syncthreads();
    for (int off = KCENT / 2; off > 0; off >>= 1) {
        if (t < off) rf[t] += rf[t + off];
        __syncthreads();
    }
    float ntot = rf[0];
    cs[t] = (cls + EPS_) / (ntot + KCENT * EPS_) * ntot;

    sa[t] = c;
    __syncthreads();
    int* pin = sa; int* pout = sb;
    for (int off = 1; off < KCENT; off <<= 1) {
        pout[t] = pin[t] + ((t >= off) ? pin[t - off] : 0);
        __syncthreads();
        int* tmp = pin; pin = pout; pout = tmp;
    }
    int excl = pin[t] - c;
    start[t] = excl;
    cursor16[t * 16] = excl;   // one cursor per 64B line
}

// ---------- K4: scatter rows into cluster-sorted order (+sorted keys) ----------
__global__ __launch_bounds__(256) void k_scatter(
    const int* __restrict__ ind, int* __restrict__ cursor16,
    int* __restrict__ perm, int* __restrict__ key) {
    int n = blockIdx.x * 256 + threadIdx.x;
    int bi = ind[n];
    int pos = atomicAdd(&cursor16[bi * 16], 1);
    perm[pos] = n;
    key[pos]  = bi;
}

// ---------- K5: segment sum over uniform 32-row wave-windows ----------
__global__ __launch_bounds__(256) void k_segsum(
    const float* __restrict__ x, const int* __restrict__ perm,
    const int* __restrict__ key, float* __restrict__ csum) {
    const int wgid = blockIdx.x * 4 + (threadIdx.x >> 6);  // 0..4095
    const int lane = threadIdx.x & 63;
    const int r0   = wgid * 32;

    float acc = 0.f;
    int cur = key[r0];
#pragma unroll 4
    for (int r = r0; r < r0 + 32; r += 2) {
        int k0 = key[r];                  // wave-uniform -> scalar load
        int k1 = key[r + 1];
        int p0 = perm[r];
        int p1 = perm[r + 1];
        float v0 = x[(size_t)p0 * DIM + lane];   // coalesced 256B/row
        float v1 = x[(size_t)p1 * DIM + lane];
        if (k0 != cur) {                  // wave-uniform branch, rare
            atomicAdd(&csum[(size_t)cur * DIM + lane], acc);
            acc = 0.f; cur = k0;
        }
        acc += v0;
        if (k1 != cur) {
            atomicAdd(&csum[(size_t)cur * DIM + lane], acc);
            acc = 0.f; cur = k1;
        }
        acc += v1;
    }
    atomicAdd(&csum[(size_t)cur * DIM + lane], acc);
}

// ---------- K6: centroids_new, stored transposed [K][D] ----------
__global__ void k_newcent(const float* __restrict__ avg,
                          const float* __restrict__ csum,
                          const float* __restrict__ cs,
                          float* __restrict__ cnewT) {
    int idx = blockIdx.x * blockDim.x + threadIdx.x;  // = k*64 + d
    int k = idx >> 6, d = idx & 63;
    float v = DECAY * avg[d * KCENT + k] + (1.0f - DECAY) * csum[idx];
    cnewT[idx] = v / cs[k];
}

// ---------- K7: gather quantized rows + MSE loss ----------
__global__ __launch_bounds__(256) void k_out(
    const float* __restrict__ x, const int* __restrict__ ind,
    const float* __restrict__ cnewT, float* __restrict__ out,
    float* __restrict__ loss) {
    const int tid = threadIdx.x;
    const int l16 = tid & 15;
    float p = 0.f;

    for (int g = blockIdx.x; g < NROWS / 16; g += 2048) {
        int row = g * 16 + (tid >> 4);
        int k = ind[row];
        float4 q  = ((const float4*)(cnewT + (size_t)k * DIM))[l16];
        float4 xw = ((const float4*)(x + (size_t)row * DIM))[l16];
        ((float4*)(out + (size_t)row * DIM))[l16] = q;
        float dx = xw.x - q.x, dy = xw.y - q.y, dz = xw.z - q.z, dw = xw.w - q.w;
        p += dx * dx + dy * dy + dz * dz + dw * dw;
    }

    __shared__ float red[256];
    red[tid] = p;
    __syncthreads();
    for (int off = 128; off > 0; off >>= 1) {
        if (tid < off) red[tid] += red[tid + off];
        __syncthreads();
    }
    if (tid == 0)
        atomicAdd(loss, red[0] * (1.0f / ((float)NROWS * (float)DIM)));
}

extern "C" void kernel_launch(void* const* d_in, const int* in_sizes, int n_in,
                              void* d_out, int out_size, void* d_ws, size_t ws_size,
                              hipStream_t stream) {
    const float* x            = (const float*)d_in[0];
    const float* cent         = (const float*)d_in[1];
    const float* cluster_size = (const float*)d_in[2];
    const float* avg          = (const float*)d_in[3];
    float* out = (float*)d_out;

    float* ws       = (float*)d_ws;
    float* csum     = ws;                     // K*D (zeroed)
    int*   cnt      = (int*)(ws + 65536);     // K (zeroed, contiguous with csum)
    float* cs       = ws + 66560;             // K
    float* cnewT    = ws + 67584;             // K*D
    int*   ind      = (int*)(ws + 133120);    // N
    int*   perm     = (int*)(ws + 264192);    // N
    int*   key      = (int*)(ws + 395264);    // N
    int*   start    = (int*)(ws + 526336);    // K
    int*   cursor16 = (int*)(ws + 527360);    // 16K
    u32*   centB    = (u32*)(ws + 543744);    // K*68

    hipMemsetAsync(csum, 0, (65536 + 1024) * sizeof(float), stream);  // csum + cnt
    hipMemsetAsync(out + (size_t)NROWS * DIM, 0, sizeof(float), stream);  // loss slot

    k_ctrans <<<KCENT / 256, 256, 0, stream>>>(cent, centB);
    k_assign <<<NROWS / 256, 256, 0, stream>>>(x, centB, ind, cnt);
    k_scan   <<<1, KCENT, 0, stream>>>(cluster_size, cnt, cs, start, cursor16);
    k_scatter<<<NROWS / 256, 256, 0, stream>>>(ind, cursor16, perm, key);
    k_segsum <<<NROWS / 128, 256, 0, stream>>>(x, perm, key, csum);
    k_newcent<<<(KCENT * DIM) / 256, 256, 0, stream>>>(avg, csum, cs, cnewT);
    k_out    <<<2048, 256, 0, stream>>>(x, ind, cnewT, out,
                                        out + (size_t)NROWS * DIM);
}

// Round 8
// 276.972 us; speedup vs baseline: 3.8167x; 1.0629x over previous
//
#include <hip/hip_runtime.h>
#include <math.h>

#define NROWS 131072
#define DIM   64
#define KCENT 1024
#define DECAY 0.99f
#define EPS_  1e-5f

typedef unsigned int u32;
typedef unsigned short u16;
typedef __attribute__((ext_vector_type(8))) short short8b;
typedef __attribute__((ext_vector_type(16))) float floatx16;

// ---------------- ws layout (float elements) ----------------
// csum    [K*D]    @ 0        (zeroed by k_ctrans)
// cnt     [K]      @ 65536    (int, zeroed by k_ctrans)
// cs      [K]      @ 66560
// cnewT   [K*D]    @ 67584
// ind     [N]      @ 133120   (int)
// pk      [N]      @ 264192   (int2: {row, cluster} in sorted order)
// start   [K]      @ 526336   (int)
// cursor16[K*16]   @ 527360   (int, 64B-spread atomic cursors)
// centB   [K*68]   @ 543744   (u32: bf16 hi 32dw | lo 32dw | csq@64 | pad; 272B rows)

__device__ inline u16 bf16rne(float f) {
    u32 u = __float_as_uint(f);
    return (u16)((u + 0x7FFFu + ((u >> 16) & 1u)) >> 16);
}

// ---------- K1: centroid transpose/split + zero csum/cnt ----------
__global__ void k_ctrans(const float* __restrict__ cent, u32* __restrict__ centB,
                         float* __restrict__ zero_base) {
    int tid = blockIdx.x * 256 + threadIdx.x;   // 0..1023
    // zero csum+cnt (66560 floats = 16640 float4)
    float4 z = make_float4(0.f, 0.f, 0.f, 0.f);
    for (int i = tid; i < 16640; i += 1024) ((float4*)zero_base)[i] = z;

    int k = tid;
    u32* row = centB + (size_t)k * 68;
    float csq = 0.f;
#pragma unroll
    for (int d0 = 0; d0 < 32; ++d0) {
        float f0 = cent[(2 * d0) * KCENT + k];      // coalesced across lanes
        float f1 = cent[(2 * d0 + 1) * KCENT + k];
        u16 h0 = bf16rne(f0), h1 = bf16rne(f1);
        u16 s0 = bf16rne(f0 - __uint_as_float((u32)h0 << 16));
        u16 s1 = bf16rne(f1 - __uint_as_float((u32)h1 << 16));
        csq = fmaf(f0, f0, fmaf(f1, f1, csq));
        row[d0]      = (u32)h0 | ((u32)h1 << 16);   // hi
        row[32 + d0] = (u32)s0 | ((u32)s1 << 16);   // lo
    }
    row[64] = __float_as_uint(csq);
}

// ---------- K2: MFMA assignment, 3-term split, 64-cent tiles ----------
// dot ~= xh.ch + xh.cl + xl.ch  (lo*lo dropped: ~2^-18 rel, below split residual)
// C layout (m74/m101): col=lane&31, row=(reg&3)+8*(reg>>2)+4*(lane>>5).
__global__ __launch_bounds__(256, 2) void k_assign(
    const float* __restrict__ x, const u32* __restrict__ centB,
    int* __restrict__ ind, int* __restrict__ cnt) {
    __shared__ __align__(16) char buf[2][17408];   // 64 cents x 272B
    __shared__ int hist[KCENT];
    const int tid  = threadIdx.x;
    const int lane = tid & 63;
    const int wid  = tid >> 6;
    const int half = lane >> 5;
    const int nl   = lane & 31;
#pragma unroll
    for (int i = 0; i < KCENT / 256; ++i) hist[tid + i * 256] = 0;

    const int rowbase = blockIdx.x * 256 + wid * 64;

    // A-frags: 4 hi + 4 lo per row-group (dims t4*16+half*8 .. +8)
    short8b ah[2][4], al[2][4];
#pragma unroll
    for (int rg = 0; rg < 2; ++rg) {
        const float* xr = x + (size_t)(rowbase + rg * 32 + nl) * DIM;
#pragma unroll
        for (int t4 = 0; t4 < 4; ++t4) {
            int d0 = t4 * 16 + half * 8;
            float4 f0 = *(const float4*)(xr + d0);
            float4 f1 = *(const float4*)(xr + d0 + 4);
            float fv[8] = {f0.x, f0.y, f0.z, f0.w, f1.x, f1.y, f1.z, f1.w};
            short8b va, vb;
#pragma unroll
            for (int j = 0; j < 8; ++j) {
                u16 h = bf16rne(fv[j]);
                float lo = fv[j] - __uint_as_float((u32)h << 16);
                va[j] = (short)h;
                vb[j] = (short)bf16rne(lo);
            }
            ah[rg][t4] = va;
            al[rg][t4] = vb;
        }
    }

    float best[2][16];
    int   bidx[2][16];
#pragma unroll
    for (int rg = 0; rg < 2; ++rg)
#pragma unroll
        for (int r = 0; r < 16; ++r) { best[rg][r] = 3.402823466e38f; bidx[rg][r] = 0; }

    // tile = 64 cents = 1088 granules of 16B; 16 tiles total
    const float4* gsrc = (const float4*)centB;
    float4 pf0, pf1, pf2, pf3, pft;
    pf0 = gsrc[tid];
    pf1 = gsrc[tid + 256];
    pf2 = gsrc[tid + 512];
    pf3 = gsrc[tid + 768];
    if (tid < 64) pft = gsrc[tid + 1024];

    for (int kt = 0; kt < 16; ++kt) {
        char* b = buf[kt & 1];
        *(float4*)(b + (size_t)tid * 16)         = pf0;
        *(float4*)(b + (size_t)(tid + 256) * 16) = pf1;
        *(float4*)(b + (size_t)(tid + 512) * 16) = pf2;
        *(float4*)(b + (size_t)(tid + 768) * 16) = pf3;
        if (tid < 64) *(float4*)(b + (size_t)(tid + 1024) * 16) = pft;
        __syncthreads();
        if (kt < 15) {                               // prefetch next tile
            size_t gb = (size_t)(kt + 1) * 1088;
            pf0 = gsrc[gb + tid];
            pf1 = gsrc[gb + tid + 256];
            pf2 = gsrc[gb + tid + 512];
            pf3 = gsrc[gb + tid + 768];
            if (tid < 64) pft = gsrc[gb + tid + 1024];
        }

#pragma unroll
        for (int sub = 0; sub < 2; ++sub) {
            const char* base = b + (size_t)(sub * 32 + nl) * 272 + half * 16;
            short8b bh[4], bl[4];
#pragma unroll
            for (int t4 = 0; t4 < 4; ++t4) bh[t4] = *(const short8b*)(base + t4 * 32);
#pragma unroll
            for (int t4 = 0; t4 < 4; ++t4) bl[t4] = *(const short8b*)(base + 128 + t4 * 32);
            float cq  = *(const float*)(b + (size_t)(sub * 32 + nl) * 272 + 256);
            int  cidx = kt * 64 + sub * 32 + nl;

#pragma unroll
            for (int rg = 0; rg < 2; ++rg) {
                floatx16 acc;
#pragma unroll
                for (int i = 0; i < 16; ++i) acc[i] = 0.f;
#pragma unroll
                for (int t4 = 0; t4 < 4; ++t4)
                    acc = __builtin_amdgcn_mfma_f32_32x32x16_bf16(ah[rg][t4], bh[t4], acc, 0, 0, 0);
#pragma unroll
                for (int t4 = 0; t4 < 4; ++t4)
                    acc = __builtin_amdgcn_mfma_f32_32x32x16_bf16(ah[rg][t4], bl[t4], acc, 0, 0, 0);
#pragma unroll
                for (int t4 = 0; t4 < 4; ++t4)
                    acc = __builtin_amdgcn_mfma_f32_32x32x16_bf16(al[rg][t4], bh[t4], acc, 0, 0, 0);
#pragma unroll
                for (int r = 0; r < 16; ++r) {
                    float dist = fmaf(-2.0f, acc[r], cq);
                    if (dist < best[rg][r]) { best[rg][r] = dist; bidx[rg][r] = cidx; }
                }
            }
        }
        __syncthreads();
    }

    // cross-lane argmin within each 32-lane half
#pragma unroll
    for (int rg = 0; rg < 2; ++rg) {
#pragma unroll
        for (int r = 0; r < 16; ++r) {
            float b0 = best[rg][r]; int i0 = bidx[rg][r];
#pragma unroll
            for (int m = 1; m < 32; m <<= 1) {
                float bp = __shfl_xor(b0, m, 64);
                int   ip = __shfl_xor(i0, m, 64);
                if (bp < b0 || (bp == b0 && ip < i0)) { b0 = bp; i0 = ip; }
            }
            best[rg][r] = b0; bidx[rg][r] = i0;
        }
    }
    if (nl == 0) {
#pragma unroll
        for (int rg = 0; rg < 2; ++rg) {
            int rb = rowbase + rg * 32;
#pragma unroll
            for (int r = 0; r < 16; ++r) {
                int m = (r & 3) + 8 * (r >> 2) + 4 * half;
                ind[rb + m] = bidx[rg][r];
                atomicAdd(&hist[bidx[rg][r]], 1);
            }
        }
    }
    __syncthreads();
#pragma unroll
    for (int i = 0; i < KCENT / 256; ++i) {
        int bkt = tid + i * 256;
        int v = hist[bkt];
        if (v) atomicAdd(&cnt[bkt], v);
    }
}

// ---------- K3: EMA stats + Laplace cs + prefix sum (shuffle-scan, 2 barriers) ----------
__global__ void k_scan(const float* __restrict__ cluster_size,
                       const int* __restrict__ cnt,
                       float* __restrict__ cs,
                       int* __restrict__ start, int* __restrict__ cursor16,
                       float* __restrict__ loss) {
    __shared__ float wsumf[16];
    __shared__ int   wtot[16];
    __shared__ int   woff[16];
    __shared__ float ftot_s;
    const int t = threadIdx.x;           // 0..1023
    const int lane = t & 63, w = t >> 6;
    const int c = cnt[t];
    float cls = DECAY * cluster_size[t] + (1.0f - DECAY) * (float)c;

    // wave reduce (float) + wave inclusive scan (int)
    float s = cls;
#pragma unroll
    for (int m = 1; m < 64; m <<= 1) s += __shfl_xor(s, m, 64);
    int inc = c;
#pragma unroll
    for (int m = 1; m < 64; m <<= 1) {
        int u = __shfl_up(inc, m, 64);
        if (lane >= m) inc += u;
    }
    if (lane == 0)  wsumf[w] = s;
    if (lane == 63) wtot[w]  = inc;
    __syncthreads();
    if (t == 0) {
        int run = 0; float ft = 0.f;
#pragma unroll
        for (int i = 0; i < 16; ++i) { woff[i] = run; run += wtot[i]; ft += wsumf[i]; }
        ftot_s = ft;
        loss[0] = 0.f;                 // fold loss-slot zeroing here
    }
    __syncthreads();
    float ntot = ftot_s;
    cs[t] = (cls + EPS_) / (ntot + KCENT * EPS_) * ntot;
    int excl = woff[w] + inc - c;
    start[t] = excl;
    cursor16[t * 16] = excl;
}

// ---------- K4: scatter rows into cluster-sorted order ----------
__global__ __launch_bounds__(256) void k_scatter(
    const int* __restrict__ ind, int* __restrict__ cursor16,
    int2* __restrict__ pk) {
    int n = blockIdx.x * 256 + threadIdx.x;
    int bi = ind[n];
    int pos = atomicAdd(&cursor16[bi * 16], 1);
    pk[pos] = make_int2(n, bi);        // one 8B store instead of two scattered 4B
}

// ---------- K5: segment sum over uniform 32-row wave-windows ----------
__global__ __launch_bounds__(256) void k_segsum(
    const float* __restrict__ x, const int2* __restrict__ pk,
    float* __restrict__ csum) {
    const int wgid = blockIdx.x * 4 + (threadIdx.x >> 6);  // 0..4095
    const int lane = threadIdx.x & 63;
    const int r0   = wgid * 32;

    float acc = 0.f;
    int cur = pk[r0].y;
#pragma unroll 4
    for (int r = r0; r < r0 + 32; r += 2) {
        int2 a = pk[r];                   // wave-uniform -> scalar 8B load
        int2 b = pk[r + 1];
        float v0 = x[(size_t)a.x * DIM + lane];   // coalesced 256B/row
        float v1 = x[(size_t)b.x * DIM + lane];
        if (a.y != cur) {                 // wave-uniform branch, rare
            atomicAdd(&csum[(size_t)cur * DIM + lane], acc);
            acc = 0.f; cur = a.y;
        }
        acc += v0;
        if (b.y != cur) {
            atomicAdd(&csum[(size_t)cur * DIM + lane], acc);
            acc = 0.f; cur = b.y;
        }
        acc += v1;
    }
    atomicAdd(&csum[(size_t)cur * DIM + lane], acc);
}

// ---------- K6: centroids_new, stored transposed [K][D] ----------
__global__ void k_newcent(const float* __restrict__ avg,
                          const float* __restrict__ csum,
                          const float* __restrict__ cs,
                          float* __restrict__ cnewT) {
    int idx = blockIdx.x * blockDim.x + threadIdx.x;  // = k*64 + d
    int k = idx >> 6, d = idx & 63;
    float v = DECAY * avg[d * KCENT + k] + (1.0f - DECAY) * csum[idx];
    cnewT[idx] = v / cs[k];
}

// ---------- K7: gather quantized rows + MSE loss ----------
__global__ __launch_bounds__(256) void k_out(
    const float* __restrict__ x, const int* __restrict__ ind,
    const float* __restrict__ cnewT, float* __restrict__ out,
    float* __restrict__ loss) {
    const int tid = threadIdx.x;
    const int l16 = tid & 15;
    float p = 0.f;

    for (int g = blockIdx.x; g < NROWS / 16; g += 2048) {
        int row = g * 16 + (tid >> 4);
        int k = ind[row];
        float4 q  = ((const float4*)(cnewT + (size_t)k * DIM))[l16];
        float4 xw = ((const float4*)(x + (size_t)row * DIM))[l16];
        ((float4*)(out + (size_t)row * DIM))[l16] = q;
        float dx = xw.x - q.x, dy = xw.y - q.y, dz = xw.z - q.z, dw = xw.w - q.w;
        p += dx * dx + dy * dy + dz * dz + dw * dw;
    }

    __shared__ float red[256];
    red[tid] = p;
    __syncthreads();
    for (int off = 128; off > 0; off >>= 1) {
        if (tid < off) red[tid] += red[tid + off];
        __syncthreads();
    }
    if (tid == 0)
        atomicAdd(loss, red[0] * (1.0f / ((float)NROWS * (float)DIM)));
}

extern "C" void kernel_launch(void* const* d_in, const int* in_sizes, int n_in,
                              void* d_out, int out_size, void* d_ws, size_t ws_size,
                              hipStream_t stream) {
    const float* x            = (const float*)d_in[0];
    const float* cent         = (const float*)d_in[1];
    const float* cluster_size = (const float*)d_in[2];
    const float* avg          = (const float*)d_in[3];
    float* out = (float*)d_out;

    float* ws       = (float*)d_ws;
    float* csum     = ws;                     // K*D
    int*   cnt      = (int*)(ws + 65536);     // K
    float* cs       = ws + 66560;             // K
    float* cnewT    = ws + 67584;             // K*D
    int*   ind      = (int*)(ws + 133120);    // N
    int2*  pk       = (int2*)(ws + 264192);   // N int2
    int*   start    = (int*)(ws + 526336);    // K
    int*   cursor16 = (int*)(ws + 527360);    // 16K
    u32*   centB    = (u32*)(ws + 543744);    // K*68
    float* loss     = out + (size_t)NROWS * DIM;

    k_ctrans <<<KCENT / 256, 256, 0, stream>>>(cent, centB, csum);
    k_assign <<<NROWS / 256, 256, 0, stream>>>(x, centB, ind, cnt);
    k_scan   <<<1, KCENT, 0, stream>>>(cluster_size, cnt, cs, start, cursor16, loss);
    k_scatter<<<NROWS / 256, 256, 0, stream>>>(ind, cursor16, pk);
    k_segsum <<<NROWS / 128, 256, 0, stream>>>(x, pk, csum);
    k_newcent<<<(KCENT * DIM) / 256, 256, 0, stream>>>(avg, csum, cs, cnewT);
    k_out    <<<2048, 256, 0, stream>>>(x, ind, cnewT, out, loss);
}

// Round 9
// 218.721 us; speedup vs baseline: 4.8332x; 1.2663x over previous
//
#include <hip/hip_runtime.h>
#include <math.h>

#define NROWS 131072
#define DIM   64
#define KCENT 1024
#define DECAY 0.99f
#define EPS_  1e-5f

typedef unsigned int u32;
typedef unsigned short u16;
typedef __attribute__((ext_vector_type(8))) short short8b;
typedef __attribute__((ext_vector_type(16))) float floatx16;

// ---------------- ws layout (float elements) ----------------
// csum    [K*D]    @ 0        (zeroed by k_ctrans)
// cnt     [K]      @ 65536    (int, zeroed by k_ctrans)
// cs      [K]      @ 66560
// cnewT   [K*D]    @ 67584
// ind     [N]      @ 133120   (int)
// pk      [N]      @ 264192   (int2: {row, cluster} in sorted order)
// start   [K]      @ 526336   (int)
// cursor16[K*16]   @ 527360   (int, 64B-spread atomic cursors)
// centB   [K*68]   @ 543744   (u32: bf16 hi 32dw | lo 32dw | csq@64 | pad; 272B rows)

__device__ inline u16 bf16rne(float f) {
    u32 u = __float_as_uint(f);
    return (u16)((u + 0x7FFFu + ((u >> 16) & 1u)) >> 16);
}

// ---------- K1: centroid transpose/split + zero csum/cnt ----------
__global__ void k_ctrans(const float* __restrict__ cent, u32* __restrict__ centB,
                         float* __restrict__ zero_base) {
    int tid = blockIdx.x * 256 + threadIdx.x;   // 0..1023
    // zero csum+cnt (66560 floats = 16640 float4)
    float4 z = make_float4(0.f, 0.f, 0.f, 0.f);
    for (int i = tid; i < 16640; i += 1024) ((float4*)zero_base)[i] = z;

    int k = tid;
    u32* row = centB + (size_t)k * 68;
    float csq = 0.f;
#pragma unroll
    for (int d0 = 0; d0 < 32; ++d0) {
        float f0 = cent[(2 * d0) * KCENT + k];      // coalesced across lanes
        float f1 = cent[(2 * d0 + 1) * KCENT + k];
        u16 h0 = bf16rne(f0), h1 = bf16rne(f1);
        u16 s0 = bf16rne(f0 - __uint_as_float((u32)h0 << 16));
        u16 s1 = bf16rne(f1 - __uint_as_float((u32)h1 << 16));
        csq = fmaf(f0, f0, fmaf(f1, f1, csq));
        row[d0]      = (u32)h0 | ((u32)h1 << 16);   // hi
        row[32 + d0] = (u32)s0 | ((u32)s1 << 16);   // lo
    }
    row[64] = __float_as_uint(csq);
}

// ---------- K2: MFMA assignment, 3-term split, 64-cent tiles ----------
// dot ~= xh.ch + xh.cl + xl.ch  (lo*lo dropped: ~2^-18 rel, below split residual)
// C layout (m74/m101): col=lane&31, row=(reg&3)+8*(reg>>2)+4*(lane>>5).
__global__ __launch_bounds__(256, 2) void k_assign(
    const float* __restrict__ x, const u32* __restrict__ centB,
    int* __restrict__ ind, int* __restrict__ cnt) {
    __shared__ __align__(16) char buf[2][17408];   // 64 cents x 272B
    __shared__ int hist[KCENT];
    const int tid  = threadIdx.x;
    const int lane = tid & 63;
    const int wid  = tid >> 6;
    const int half = lane >> 5;
    const int nl   = lane & 31;
#pragma unroll
    for (int i = 0; i < KCENT / 256; ++i) hist[tid + i * 256] = 0;

    const int rowbase = blockIdx.x * 256 + wid * 64;

    // A-frags: 4 hi + 4 lo per row-group (dims t4*16+half*8 .. +8)
    short8b ah[2][4], al[2][4];
#pragma unroll
    for (int rg = 0; rg < 2; ++rg) {
        const float* xr = x + (size_t)(rowbase + rg * 32 + nl) * DIM;
#pragma unroll
        for (int t4 = 0; t4 < 4; ++t4) {
            int d0 = t4 * 16 + half * 8;
            float4 f0 = *(const float4*)(xr + d0);
            float4 f1 = *(const float4*)(xr + d0 + 4);
            float fv[8] = {f0.x, f0.y, f0.z, f0.w, f1.x, f1.y, f1.z, f1.w};
            short8b va, vb;
#pragma unroll
            for (int j = 0; j < 8; ++j) {
                u16 h = bf16rne(fv[j]);
                float lo = fv[j] - __uint_as_float((u32)h << 16);
                va[j] = (short)h;
                vb[j] = (short)bf16rne(lo);
            }
            ah[rg][t4] = va;
            al[rg][t4] = vb;
        }
    }

    float best[2][16];
    int   bidx[2][16];
#pragma unroll
    for (int rg = 0; rg < 2; ++rg)
#pragma unroll
        for (int r = 0; r < 16; ++r) { best[rg][r] = 3.402823466e38f; bidx[rg][r] = 0; }

    // tile = 64 cents = 1088 granules of 16B; 16 tiles total
    const float4* gsrc = (const float4*)centB;
    float4 pf0, pf1, pf2, pf3, pft;
    pf0 = gsrc[tid];
    pf1 = gsrc[tid + 256];
    pf2 = gsrc[tid + 512];
    pf3 = gsrc[tid + 768];
    if (tid < 64) pft = gsrc[tid + 1024];

    for (int kt = 0; kt < 16; ++kt) {
        char* b = buf[kt & 1];
        *(float4*)(b + (size_t)tid * 16)         = pf0;
        *(float4*)(b + (size_t)(tid + 256) * 16) = pf1;
        *(float4*)(b + (size_t)(tid + 512) * 16) = pf2;
        *(float4*)(b + (size_t)(tid + 768) * 16) = pf3;
        if (tid < 64) *(float4*)(b + (size_t)(tid + 1024) * 16) = pft;
        __syncthreads();
        if (kt < 15) {                               // prefetch next tile
            size_t gb = (size_t)(kt + 1) * 1088;
            pf0 = gsrc[gb + tid];
            pf1 = gsrc[gb + tid + 256];
            pf2 = gsrc[gb + tid + 512];
            pf3 = gsrc[gb + tid + 768];
            if (tid < 64) pft = gsrc[gb + tid + 1024];
        }

#pragma unroll
        for (int sub = 0; sub < 2; ++sub) {
            const char* base = b + (size_t)(sub * 32 + nl) * 272 + half * 16;
            short8b bh[4], bl[4];
#pragma unroll
            for (int t4 = 0; t4 < 4; ++t4) bh[t4] = *(const short8b*)(base + t4 * 32);
#pragma unroll
            for (int t4 = 0; t4 < 4; ++t4) bl[t4] = *(const short8b*)(base + 128 + t4 * 32);
            float cq  = *(const float*)(b + (size_t)(sub * 32 + nl) * 272 + 256);
            int  cidx = kt * 64 + sub * 32 + nl;

#pragma unroll
            for (int rg = 0; rg < 2; ++rg) {
                floatx16 acc;
#pragma unroll
                for (int i = 0; i < 16; ++i) acc[i] = 0.f;
#pragma unroll
                for (int t4 = 0; t4 < 4; ++t4)
                    acc = __builtin_amdgcn_mfma_f32_32x32x16_bf16(ah[rg][t4], bh[t4], acc, 0, 0, 0);
#pragma unroll
                for (int t4 = 0; t4 < 4; ++t4)
                    acc = __builtin_amdgcn_mfma_f32_32x32x16_bf16(ah[rg][t4], bl[t4], acc, 0, 0, 0);
#pragma unroll
                for (int t4 = 0; t4 < 4; ++t4)
                    acc = __builtin_amdgcn_mfma_f32_32x32x16_bf16(al[rg][t4], bh[t4], acc, 0, 0, 0);
#pragma unroll
                for (int r = 0; r < 16; ++r) {
                    float dist = fmaf(-2.0f, acc[r], cq);
                    if (dist < best[rg][r]) { best[rg][r] = dist; bidx[rg][r] = cidx; }
                }
            }
        }
        __syncthreads();
    }

    // cross-lane argmin within each 32-lane half
#pragma unroll
    for (int rg = 0; rg < 2; ++rg) {
#pragma unroll
        for (int r = 0; r < 16; ++r) {
            float b0 = best[rg][r]; int i0 = bidx[rg][r];
#pragma unroll
            for (int m = 1; m < 32; m <<= 1) {
                float bp = __shfl_xor(b0, m, 64);
                int   ip = __shfl_xor(i0, m, 64);
                if (bp < b0 || (bp == b0 && ip < i0)) { b0 = bp; i0 = ip; }
            }
            best[rg][r] = b0; bidx[rg][r] = i0;
        }
    }
    if (nl == 0) {
#pragma unroll
        for (int rg = 0; rg < 2; ++rg) {
            int rb = rowbase + rg * 32;
#pragma unroll
            for (int r = 0; r < 16; ++r) {
                int m = (r & 3) + 8 * (r >> 2) + 4 * half;
                ind[rb + m] = bidx[rg][r];
                atomicAdd(&hist[bidx[rg][r]], 1);
            }
        }
    }
    __syncthreads();
#pragma unroll
    for (int i = 0; i < KCENT / 256; ++i) {
        int bkt = tid + i * 256;
        int v = hist[bkt];
        if (v) atomicAdd(&cnt[bkt], v);
    }
}

// ---------- K3: EMA stats + Laplace cs + prefix sum (shuffle-scan, 2 barriers) ----------
__global__ void k_scan(const float* __restrict__ cluster_size,
                       const int* __restrict__ cnt,
                       float* __restrict__ cs,
                       int* __restrict__ start, int* __restrict__ cursor16,
                       float* __restrict__ loss) {
    __shared__ float wsumf[16];
    __shared__ int   wtot[16];
    __shared__ int   woff[16];
    __shared__ float ftot_s;
    const int t = threadIdx.x;           // 0..1023
    const int lane = t & 63, w = t >> 6;
    const int c = cnt[t];
    float cls = DECAY * cluster_size[t] + (1.0f - DECAY) * (float)c;

    // wave reduce (float) + wave inclusive scan (int)
    float s = cls;
#pragma unroll
    for (int m = 1; m < 64; m <<= 1) s += __shfl_xor(s, m, 64);
    int inc = c;
#pragma unroll
    for (int m = 1; m < 64; m <<= 1) {
        int u = __shfl_up(inc, m, 64);
        if (lane >= m) inc += u;
    }
    if (lane == 0)  wsumf[w] = s;
    if (lane == 63) wtot[w]  = inc;
    __syncthreads();
    if (t == 0) {
        int run = 0; float ft = 0.f;
#pragma unroll
        for (int i = 0; i < 16; ++i) { woff[i] = run; run += wtot[i]; ft += wsumf[i]; }
        ftot_s = ft;
        loss[0] = 0.f;                 // fold loss-slot zeroing here
    }
    __syncthreads();
    float ntot = ftot_s;
    cs[t] = (cls + EPS_) / (ntot + KCENT * EPS_) * ntot;
    int excl = woff[w] + inc - c;
    start[t] = excl;
    cursor16[t * 16] = excl;
}

// ---------- K4: scatter with block-aggregated ranks ----------
// Longest per-address global atomic chain drops from max-cluster-size (~5K)
// to <= #blocks (512). LDS atomic old-value = intra-block rank.
__global__ __launch_bounds__(256) void k_scatter(
    const int* __restrict__ ind, int* __restrict__ cursor16,
    int2* __restrict__ pk) {
    __shared__ int lh[KCENT];
#pragma unroll
    for (int i = 0; i < KCENT / 256; ++i) lh[threadIdx.x + i * 256] = 0;
    __syncthreads();

    const int n  = blockIdx.x * 256 + threadIdx.x;
    const int bi = ind[n];
    const int rank = atomicAdd(&lh[bi], 1);   // LDS atomic: old = my rank
    __syncthreads();

#pragma unroll
    for (int i = 0; i < KCENT / 256; ++i) {
        int k = threadIdx.x + i * 256;
        int c = lh[k];
        int base = 0;
        if (c) base = atomicAdd(&cursor16[k * 16], c);  // one per distinct cluster
        lh[k] = base;
    }
    __syncthreads();

    pk[lh[bi] + rank] = make_int2(n, bi);
}

// ---------- K5: segment sum over uniform 32-row wave-windows ----------
__global__ __launch_bounds__(256) void k_segsum(
    const float* __restrict__ x, const int2* __restrict__ pk,
    float* __restrict__ csum) {
    const int wgid = blockIdx.x * 4 + (threadIdx.x >> 6);  // 0..4095
    const int lane = threadIdx.x & 63;
    const int r0   = wgid * 32;

    float acc = 0.f;
    int cur = pk[r0].y;
#pragma unroll 4
    for (int r = r0; r < r0 + 32; r += 2) {
        int2 a = pk[r];                   // wave-uniform -> scalar 8B load
        int2 b = pk[r + 1];
        float v0 = x[(size_t)a.x * DIM + lane];   // coalesced 256B/row
        float v1 = x[(size_t)b.x * DIM + lane];
        if (a.y != cur) {                 // wave-uniform branch, rare
            atomicAdd(&csum[(size_t)cur * DIM + lane], acc);
            acc = 0.f; cur = a.y;
        }
        acc += v0;
        if (b.y != cur) {
            atomicAdd(&csum[(size_t)cur * DIM + lane], acc);
            acc = 0.f; cur = b.y;
        }
        acc += v1;
    }
    atomicAdd(&csum[(size_t)cur * DIM + lane], acc);
}

// ---------- K6: centroids_new, stored transposed [K][D] ----------
__global__ void k_newcent(const float* __restrict__ avg,
                          const float* __restrict__ csum,
                          const float* __restrict__ cs,
                          float* __restrict__ cnewT) {
    int idx = blockIdx.x * blockDim.x + threadIdx.x;  // = k*64 + d
    int k = idx >> 6, d = idx & 63;
    float v = DECAY * avg[d * KCENT + k] + (1.0f - DECAY) * csum[idx];
    cnewT[idx] = v / cs[k];
}

// ---------- K7: gather quantized rows + MSE loss ----------
__global__ __launch_bounds__(256) void k_out(
    const float* __restrict__ x, const int* __restrict__ ind,
    const float* __restrict__ cnewT, float* __restrict__ out,
    float* __restrict__ loss) {
    const int tid = threadIdx.x;
    const int l16 = tid & 15;
    float p = 0.f;

    for (int g = blockIdx.x; g < NROWS / 16; g += 2048) {
        int row = g * 16 + (tid >> 4);
        int k = ind[row];
        float4 q  = ((const float4*)(cnewT + (size_t)k * DIM))[l16];
        float4 xw = ((const float4*)(x + (size_t)row * DIM))[l16];
        ((float4*)(out + (size_t)row * DIM))[l16] = q;
        float dx = xw.x - q.x, dy = xw.y - q.y, dz = xw.z - q.z, dw = xw.w - q.w;
        p += dx * dx + dy * dy + dz * dz + dw * dw;
    }

    __shared__ float red[256];
    red[tid] = p;
    __syncthreads();
    for (int off = 128; off > 0; off >>= 1) {
        if (tid < off) red[tid] += red[tid + off];
        __syncthreads();
    }
    if (tid == 0)
        atomicAdd(loss, red[0] * (1.0f / ((float)NROWS * (float)DIM)));
}

extern "C" void kernel_launch(void* const* d_in, const int* in_sizes, int n_in,
                              void* d_out, int out_size, void* d_ws, size_t ws_size,
                              hipStream_t stream) {
    const float* x            = (const float*)d_in[0];
    const float* cent         = (const float*)d_in[1];
    const float* cluster_size = (const float*)d_in[2];
    const float* avg          = (const float*)d_in[3];
    float* out = (float*)d_out;

    float* ws       = (float*)d_ws;
    float* csum     = ws;                     // K*D
    int*   cnt      = (int*)(ws + 65536);     // K
    float* cs       = ws + 66560;             // K
    float* cnewT    = ws + 67584;             // K*D
    int*   ind      = (int*)(ws + 133120);    // N
    int2*  pk       = (int2*)(ws + 264192);   // N int2
    int*   start    = (int*)(ws + 526336);    // K
    int*   cursor16 = (int*)(ws + 527360);    // 16K
    u32*   centB    = (u32*)(ws + 543744);    // K*68
    float* loss     = out + (size_t)NROWS * DIM;

    k_ctrans <<<KCENT / 256, 256, 0, stream>>>(cent, centB, csum);
    k_assign <<<NROWS / 256, 256, 0, stream>>>(x, centB, ind, cnt);
    k_scan   <<<1, KCENT, 0, stream>>>(cluster_size, cnt, cs, start, cursor16, loss);
    k_scatter<<<NROWS / 256, 256, 0, stream>>>(ind, cursor16, pk);
    k_segsum <<<NROWS / 128, 256, 0, stream>>>(x, pk, csum);
    k_newcent<<<(KCENT * DIM) / 256, 256, 0, stream>>>(avg, csum, cs, cnewT);
    k_out    <<<2048, 256, 0, stream>>>(x, ind, cnewT, out, loss);
}